// Round 1
// baseline (798.184 us; speedup 1.0000x reference)
//
#include <hip/hip_runtime.h>

#define DFEAT 16

// One thread per (edge, quad-of-4-features). Coalesced float4 loads of x,
// 4 HW float atomics into out, lane q==0 also counts the edge.
__global__ void na_scatter_kernel(const float* __restrict__ x,
                                  const int* __restrict__ edge_dst,
                                  float* __restrict__ out,
                                  float* __restrict__ counts,
                                  int E) {
    int tid = blockIdx.x * blockDim.x + threadIdx.x;
    int e = tid >> 2;
    if (e >= E) return;
    int q = tid & 3;

    int n = edge_dst[e];
    float4 v = reinterpret_cast<const float4*>(x)[(size_t)e * 4 + q];

    float* o = out + (size_t)n * DFEAT + q * 4;
    unsafeAtomicAdd(o + 0, v.x);
    unsafeAtomicAdd(o + 1, v.y);
    unsafeAtomicAdd(o + 2, v.z);
    unsafeAtomicAdd(o + 3, v.w);

    if (q == 0) unsafeAtomicAdd(&counts[n], 1.0f);
}

// One thread per (node, quad): out[n][:] *= rsqrt(counts[n] + 1)
__global__ void na_finalize_kernel(float* __restrict__ out,
                                   const float* __restrict__ counts,
                                   int N) {
    int tid = blockIdx.x * blockDim.x + threadIdx.x;
    int n = tid >> 2;
    if (n >= N) return;

    float s = rsqrtf(counts[n] + 1.0f);
    float4 v = reinterpret_cast<float4*>(out)[tid];
    v.x *= s; v.y *= s; v.z *= s; v.w *= s;
    reinterpret_cast<float4*>(out)[tid] = v;
}

extern "C" void kernel_launch(void* const* d_in, const int* in_sizes, int n_in,
                              void* d_out, int out_size, void* d_ws, size_t ws_size,
                              hipStream_t stream) {
    const float* x        = (const float*)d_in[0];
    const int*   edge_dst = (const int*)d_in[1];
    float*       out      = (float*)d_out;
    float*       counts   = (float*)d_ws;

    const int E = in_sizes[0] / DFEAT;   // 3,200,000
    const int N = out_size / DFEAT;      // 100,000

    // Zero accumulators (harness poisons buffers with 0xAA; we must init).
    hipMemsetAsync(d_out, 0, (size_t)out_size * sizeof(float), stream);
    hipMemsetAsync(d_ws, 0, (size_t)N * sizeof(float), stream);

    {
        const int threads = E * 4;
        const int block = 256;
        const int grid = (threads + block - 1) / block;
        na_scatter_kernel<<<grid, block, 0, stream>>>(x, edge_dst, out, counts, E);
    }
    {
        const int threads = N * 4;
        const int block = 256;
        const int grid = (threads + block - 1) / block;
        na_finalize_kernel<<<grid, block, 0, stream>>>(out, counts, N);
    }
}

// Round 2
// 411.435 us; speedup vs baseline: 1.9400x; 1.9400x over previous
//
#include <hip/hip_runtime.h>

#define DFEAT 16

// ---------------- CSR-build + gather path (no float atomics) ----------------

// Pass A: histogram + per-edge rank. rank[e] = old count of dst[e].
__global__ void na_hist_rank_kernel(const int* __restrict__ edge_dst,
                                    int* __restrict__ counts,
                                    int* __restrict__ rank,
                                    int E) {
    int e = blockIdx.x * blockDim.x + threadIdx.x;
    if (e >= E) return;
    int n = edge_dst[e];
    rank[e] = atomicAdd(&counts[n], 1);
}

// Pass B: exclusive scan of counts[0..N) -> offsets[0..N]. Single block, 1024 thr.
__global__ void na_scan_kernel(const int* __restrict__ counts,
                               int* __restrict__ offsets,
                               int N) {
    __shared__ int lds[1024];
    const int tid = threadIdx.x;
    const int CH = (N + 1023) / 1024;
    const int beg = tid * CH;
    const int end = min(beg + CH, N);

    int sum = 0;
    for (int i = beg; i < end; ++i) sum += counts[i];
    lds[tid] = sum;
    __syncthreads();

    // Hillis-Steele inclusive scan over 1024 thread sums.
    for (int off = 1; off < 1024; off <<= 1) {
        int v = (tid >= off) ? lds[tid - off] : 0;
        __syncthreads();
        lds[tid] += v;
        __syncthreads();
    }
    int carry = lds[tid] - sum;  // exclusive prefix for this thread's chunk

    int run = carry;
    for (int i = beg; i < end; ++i) {
        offsets[i] = run;
        run += counts[i];
    }
    if (tid == 1023) offsets[N] = run;  // total (last chunk ends at N)
}

// Pass C: place each edge at its final slot. No atomics.
__global__ void na_fill_kernel(const int* __restrict__ edge_dst,
                               const int* __restrict__ rank,
                               const int* __restrict__ offsets,
                               int* __restrict__ edge_list,
                               int E) {
    int e = blockIdx.x * blockDim.x + threadIdx.x;
    if (e >= E) return;
    int n = edge_dst[e];
    edge_list[offsets[n] + rank[e]] = e;
}

// Pass D: gather-reduce. 16 lanes per node; each lane owns one feature.
__global__ void na_gather_kernel(const float* __restrict__ x,
                                 const int* __restrict__ edge_list,
                                 const int* __restrict__ offsets,
                                 float* __restrict__ out,
                                 int N) {
    int tid = blockIdx.x * blockDim.x + threadIdx.x;
    int node = tid >> 4;
    int f = tid & 15;
    if (node >= N) return;

    int beg = offsets[node];
    int end = offsets[node + 1];

    float acc = 0.0f;
    int i = beg;
    for (; i + 1 < end; i += 2) {
        int e0 = edge_list[i];
        int e1 = edge_list[i + 1];
        float v0 = x[(size_t)e0 * DFEAT + f];
        float v1 = x[(size_t)e1 * DFEAT + f];
        acc += v0;
        acc += v1;
    }
    if (i < end) acc += x[(size_t)edge_list[i] * DFEAT + f];

    float scale = rsqrtf((float)(end - beg) + 1.0f);
    out[(size_t)node * DFEAT + f] = acc * scale;
}

// ---------------- Fallback: round-1 atomic scatter path ----------------

__global__ void na_scatter_kernel(const float* __restrict__ x,
                                  const int* __restrict__ edge_dst,
                                  float* __restrict__ out,
                                  float* __restrict__ counts,
                                  int E) {
    int tid = blockIdx.x * blockDim.x + threadIdx.x;
    int e = tid >> 2;
    if (e >= E) return;
    int q = tid & 3;

    int n = edge_dst[e];
    float4 v = reinterpret_cast<const float4*>(x)[(size_t)e * 4 + q];

    float* o = out + (size_t)n * DFEAT + q * 4;
    unsafeAtomicAdd(o + 0, v.x);
    unsafeAtomicAdd(o + 1, v.y);
    unsafeAtomicAdd(o + 2, v.z);
    unsafeAtomicAdd(o + 3, v.w);

    if (q == 0) unsafeAtomicAdd(&counts[n], 1.0f);
}

__global__ void na_finalize_kernel(float* __restrict__ out,
                                   const float* __restrict__ counts,
                                   int N) {
    int tid = blockIdx.x * blockDim.x + threadIdx.x;
    int n = tid >> 2;
    if (n >= N) return;

    float s = rsqrtf(counts[n] + 1.0f);
    float4 v = reinterpret_cast<float4*>(out)[tid];
    v.x *= s; v.y *= s; v.z *= s; v.w *= s;
    reinterpret_cast<float4*>(out)[tid] = v;
}

extern "C" void kernel_launch(void* const* d_in, const int* in_sizes, int n_in,
                              void* d_out, int out_size, void* d_ws, size_t ws_size,
                              hipStream_t stream) {
    const float* x        = (const float*)d_in[0];
    const int*   edge_dst = (const int*)d_in[1];
    float*       out      = (float*)d_out;

    const int E = in_sizes[1];           // 3,200,000
    const int N = out_size / DFEAT;      // 100,000

    // Workspace layout (ints): counts[N] | offsets[N+1] | rank[E] | edge_list[E]
    size_t need = ((size_t)2 * N + 1 + (size_t)2 * E) * sizeof(int);

    if (ws_size >= need) {
        int* counts    = (int*)d_ws;
        int* offsets   = counts + N;
        int* rank      = offsets + N + 1;
        int* edge_list = rank + E;

        hipMemsetAsync(counts, 0, (size_t)N * sizeof(int), stream);

        const int block = 256;
        const int gridE = (E + block - 1) / block;

        na_hist_rank_kernel<<<gridE, block, 0, stream>>>(edge_dst, counts, rank, E);
        na_scan_kernel<<<1, 1024, 0, stream>>>(counts, offsets, N);
        na_fill_kernel<<<gridE, block, 0, stream>>>(edge_dst, rank, offsets, edge_list, E);

        const int gthreads = N * 16;
        const int ggrid = (gthreads + block - 1) / block;
        na_gather_kernel<<<ggrid, block, 0, stream>>>(x, edge_list, offsets, out, N);
    } else {
        // Fallback: atomic scatter (round-1 path), needs only N floats of ws.
        float* counts = (float*)d_ws;
        hipMemsetAsync(d_out, 0, (size_t)out_size * sizeof(float), stream);
        hipMemsetAsync(counts, 0, (size_t)N * sizeof(float), stream);

        const int block = 256;
        {
            const int threads = E * 4;
            const int grid = (threads + block - 1) / block;
            na_scatter_kernel<<<grid, block, 0, stream>>>(x, edge_dst, out, counts, E);
        }
        {
            const int threads = N * 4;
            const int grid = (threads + block - 1) / block;
            na_finalize_kernel<<<grid, block, 0, stream>>>(out, counts, N);
        }
    }
}

// Round 3
// 259.220 us; speedup vs baseline: 3.0792x; 1.5872x over previous
//
#include <hip/hip_runtime.h>

#define DFEAT 16
#define SCAN_BLOCKS 256
#define SCAN_THREADS 256

// Pass A: histogram + per-edge rank. rank[e] = old count of dst[e].
__global__ void na_hist_rank_kernel(const int* __restrict__ edge_dst,
                                    int* __restrict__ counts,
                                    int* __restrict__ rank,
                                    int E) {
    int e = blockIdx.x * blockDim.x + threadIdx.x;
    if (e >= E) return;
    int n = edge_dst[e];
    rank[e] = atomicAdd(&counts[n], 1);
}

// Pass B1: per-block sums of counts chunks.
__global__ void na_scan_partials(const int* __restrict__ counts,
                                 int* __restrict__ blockSums,
                                 int N) {
    __shared__ int lds[SCAN_THREADS];
    const int b = blockIdx.x, t = threadIdx.x;
    const int chb = (N + SCAN_BLOCKS - 1) / SCAN_BLOCKS;
    const int bbeg = b * chb;
    const int bend = min(bbeg + chb, N);
    const int cht = (chb + SCAN_THREADS - 1) / SCAN_THREADS;
    const int beg = min(bbeg + t * cht, bend);
    const int end = min(beg + cht, bend);

    int s = 0;
    for (int i = beg; i < end; ++i) s += counts[i];
    lds[t] = s;
    __syncthreads();
    for (int off = SCAN_THREADS / 2; off > 0; off >>= 1) {
        if (t < off) lds[t] += lds[t + off];
        __syncthreads();
    }
    if (t == 0) blockSums[b] = lds[0];
}

// Pass B2: exclusive scan of the 256 block sums; also writes offsets[N]=total.
__global__ void na_scan_blocksums(const int* __restrict__ blockSums,
                                  int* __restrict__ blockOffs,
                                  int* __restrict__ offsets,
                                  int N) {
    __shared__ int lds[SCAN_BLOCKS];
    const int t = threadIdx.x;
    const int v = blockSums[t];
    lds[t] = v;
    __syncthreads();
    for (int off = 1; off < SCAN_BLOCKS; off <<= 1) {
        int add = (t >= off) ? lds[t - off] : 0;
        __syncthreads();
        lds[t] += add;
        __syncthreads();
    }
    blockOffs[t] = lds[t] - v;  // exclusive
    if (t == SCAN_BLOCKS - 1) offsets[N] = lds[t];
}

// Pass B3: final exclusive scan, writing offsets[0..N).
__global__ void na_scan_final(const int* __restrict__ counts,
                              const int* __restrict__ blockOffs,
                              int* __restrict__ offsets,
                              int N) {
    __shared__ int lds[SCAN_THREADS];
    const int b = blockIdx.x, t = threadIdx.x;
    const int chb = (N + SCAN_BLOCKS - 1) / SCAN_BLOCKS;
    const int bbeg = b * chb;
    const int bend = min(bbeg + chb, N);
    const int cht = (chb + SCAN_THREADS - 1) / SCAN_THREADS;
    const int beg = min(bbeg + t * cht, bend);
    const int end = min(beg + cht, bend);

    int s = 0;
    for (int i = beg; i < end; ++i) s += counts[i];
    lds[t] = s;
    __syncthreads();
    // Hillis-Steele inclusive scan over thread sums.
    for (int off = 1; off < SCAN_THREADS; off <<= 1) {
        int add = (t >= off) ? lds[t - off] : 0;
        __syncthreads();
        lds[t] += add;
        __syncthreads();
    }
    int run = blockOffs[b] + lds[t] - s;  // block offset + thread-exclusive
    for (int i = beg; i < end; ++i) {
        offsets[i] = run;
        run += counts[i];
    }
}

// Pass C: place each edge at its final slot. No atomics.
__global__ void na_fill_kernel(const int* __restrict__ edge_dst,
                               const int* __restrict__ rank,
                               const int* __restrict__ offsets,
                               int* __restrict__ edge_list,
                               int E) {
    int e = blockIdx.x * blockDim.x + threadIdx.x;
    if (e >= E) return;
    int n = edge_dst[e];
    edge_list[offsets[n] + rank[e]] = e;
}

// Pass D: gather-reduce. 16 lanes per node; each lane owns one feature.
__global__ void na_gather_kernel(const float* __restrict__ x,
                                 const int* __restrict__ edge_list,
                                 const int* __restrict__ offsets,
                                 float* __restrict__ out,
                                 int N) {
    int tid = blockIdx.x * blockDim.x + threadIdx.x;
    int node = tid >> 4;
    int f = tid & 15;
    if (node >= N) return;

    int beg = offsets[node];
    int end = offsets[node + 1];

    float acc = 0.0f;
    int i = beg;
    for (; i + 3 < end; i += 4) {
        int e0 = edge_list[i];
        int e1 = edge_list[i + 1];
        int e2 = edge_list[i + 2];
        int e3 = edge_list[i + 3];
        float v0 = x[(size_t)e0 * DFEAT + f];
        float v1 = x[(size_t)e1 * DFEAT + f];
        float v2 = x[(size_t)e2 * DFEAT + f];
        float v3 = x[(size_t)e3 * DFEAT + f];
        acc += v0 + v1 + v2 + v3;
    }
    for (; i < end; ++i) acc += x[(size_t)edge_list[i] * DFEAT + f];

    float scale = rsqrtf((float)(end - beg) + 1.0f);
    out[(size_t)node * DFEAT + f] = acc * scale;
}

extern "C" void kernel_launch(void* const* d_in, const int* in_sizes, int n_in,
                              void* d_out, int out_size, void* d_ws, size_t ws_size,
                              hipStream_t stream) {
    const float* x        = (const float*)d_in[0];
    const int*   edge_dst = (const int*)d_in[1];
    float*       out      = (float*)d_out;

    const int E = in_sizes[1];           // 3,200,000
    const int N = out_size / DFEAT;      // 100,000

    // Workspace (ints): counts[N] | offsets[N+1] | rank[E] | edge_list[E]
    //                   | blockSums[256] | blockOffs[256]
    int* counts    = (int*)d_ws;
    int* offsets   = counts + N;
    int* rank      = offsets + N + 1;
    int* edge_list = rank + E;
    int* blockSums = edge_list + E;
    int* blockOffs = blockSums + SCAN_BLOCKS;

    hipMemsetAsync(counts, 0, (size_t)N * sizeof(int), stream);

    const int block = 256;
    const int gridE = (E + block - 1) / block;

    na_hist_rank_kernel<<<gridE, block, 0, stream>>>(edge_dst, counts, rank, E);
    na_scan_partials<<<SCAN_BLOCKS, SCAN_THREADS, 0, stream>>>(counts, blockSums, N);
    na_scan_blocksums<<<1, SCAN_BLOCKS, 0, stream>>>(blockSums, blockOffs, offsets, N);
    na_scan_final<<<SCAN_BLOCKS, SCAN_THREADS, 0, stream>>>(counts, blockOffs, offsets, N);
    na_fill_kernel<<<gridE, block, 0, stream>>>(edge_dst, rank, offsets, edge_list, E);

    const int gthreads = N * 16;
    const int ggrid = (gthreads + block - 1) / block;
    na_gather_kernel<<<ggrid, block, 0, stream>>>(x, edge_list, offsets, out, N);
}